// Round 4
// baseline (2337.799 us; speedup 1.0000x reference)
//
#include <hip/hip_runtime.h>

#define NN 128
#define ME 32
#define DI 64
#define NZ 96
#define ROWD 130   // R row pitch in doubles
#define ROW2 65    // in double2
#define MAXIT 5000

// ---- LDS layout (offsets in doubles). R occupies [0, 16640). Total 20104 dbl = 160832 B <= 163840.
#define OFF_YB   16640               // [12][128] ybuf (precompute) / rhspart+xpart (final)
#define OFF_U3   (OFF_YB + 1536)     // union: ypartK[4][2][128] / Kcolbuf[12][96] / ypart-loop[8][96]
#define OFF_CB   (OFF_U3 + 1152)     // c [128]
#define OFF_QBUF (OFF_CB + 128)      // q [128]
#define OFF_UB   (OFF_QBUF + 128)    // u = Rc [128] ; reused as rhsbuf in final
#define OFF_HB   (OFF_UB + 128)      // h [64]
#define OFF_BB   (OFF_HB + 64)       // b [32]
#define OFF_ZB   (OFF_BB + 32)       // z [96]
#define OFF_BASE (OFF_ZB + 96)       // base [96]
#define OFF_QBV  (OFF_BASE + 96)     // qB [96]
#define OFF_CST  (OFF_QBV + 96)      // [8]: 0=u.c 1=q.u 2=objp0 3=objp1
#define LDS_DBL  (OFF_CST + 8)

// SGPR broadcast of lane `lane` (lane may be a runtime-uniform scalar).
// CONTRACT: source v computed by ALL 64 lanes before any divergence.
__device__ __forceinline__ double rld(double v, int lane) {
  union { double d; unsigned long long u; } c; c.d = v;
  unsigned lo = (unsigned)c.u, hi = (unsigned)(c.u >> 32);
  lo = (unsigned)__builtin_amdgcn_readlane((int)lo, lane);
  hi = (unsigned)__builtin_amdgcn_readlane((int)hi, lane);
  c.u = (((unsigned long long)hi) << 32) | lo;
  return c.d;
}

// 128-dot: sum_p Gr[p] * y[p], y held across lanes: ylo=y[lane], yhi=y[64+lane].
__device__ __forceinline__ double dot128(const float* Gr, double ylo, double yhi) {
  double s0 = 0, s1 = 0, s2 = 0, s3 = 0;
#pragma unroll
  for (int p4 = 0; p4 < 16; ++p4) {
    s0 = fma((double)Gr[4*p4+0], rld(ylo, 4*p4+0), s0);
    s1 = fma((double)Gr[4*p4+1], rld(ylo, 4*p4+1), s1);
    s2 = fma((double)Gr[4*p4+2], rld(ylo, 4*p4+2), s2);
    s3 = fma((double)Gr[4*p4+3], rld(ylo, 4*p4+3), s3);
  }
#pragma unroll
  for (int p4 = 0; p4 < 16; ++p4) {
    s0 = fma((double)Gr[64+4*p4+0], rld(yhi, 4*p4+0), s0);
    s1 = fma((double)Gr[64+4*p4+1], rld(yhi, 4*p4+1), s1);
    s2 = fma((double)Gr[64+4*p4+2], rld(yhi, 4*p4+2), s2);
    s3 = fma((double)Gr[64+4*p4+3], rld(yhi, 4*p4+3), s3);
  }
  return (s0 + s1) + (s2 + s3);
}

__global__ __launch_bounds__(512, 1) void altdiff_kernel(
    const float* __restrict__ Qg, const float* __restrict__ qg,
    const float* __restrict__ Gg, const float* __restrict__ hg,
    const float* __restrict__ Ag, const float* __restrict__ bg,
    float* __restrict__ out)
{
  extern __shared__ double ldsd[];
  double2* lds2 = (double2*)ldsd;

  const int bidx = blockIdx.x;
  const int tid  = threadIdx.x;
  const int w    = tid >> 6;     // wave 0..7
  const int l    = tid & 63;     // lane

  const float* Qb = Qg + (size_t)bidx * NN * NN;
  const float* Ab = Ag + (size_t)bidx * ME * NN;
  const float* Gb = Gg + (size_t)bidx * DI * NN;
  const float* qb = qg + (size_t)bidx * NN;
  const float* hb = hg + (size_t)bidx * DI;
  const float* bv = bg + (size_t)bidx * ME;

  // stage h, b, q (f64)
  if (tid < DI) ldsd[OFF_HB + tid] = (double)hb[tid];
  else if (tid < DI + ME) ldsd[OFF_BB + tid - DI] = (double)bv[tid - DI];
  if (tid >= 128 && tid < 256) ldsd[OFF_QBUF + tid - 128] = (double)qb[tid - 128];

  // ---------------- Phase 1: M = Q + A^T A + G^T G (f64) -> LDS (rows of 130 dbl) ----------------
  {
    const int rg = tid >> 4, cg = tid & 15;   // 4x8 tile: rows 4rg.., cols 8cg..
    double acc[4][8];
    const float4* Q4 = (const float4*)Qb;
#pragma unroll
    for (int rr = 0; rr < 4; ++rr) {
      float4 q0 = Q4[((4*rg+rr) << 5) + 2*cg];
      float4 q1 = Q4[((4*rg+rr) << 5) + 2*cg + 1];
      acc[rr][0]=(double)q0.x; acc[rr][1]=(double)q0.y; acc[rr][2]=(double)q0.z; acc[rr][3]=(double)q0.w;
      acc[rr][4]=(double)q1.x; acc[rr][5]=(double)q1.y; acc[rr][6]=(double)q1.z; acc[rr][7]=(double)q1.w;
    }
    const float4* A4 = (const float4*)Ab;
    for (int m = 0; m < ME; ++m) {
      float4 u  = A4[(m << 5) + rg];                       // A[m][4rg..4rg+3]
      float4 v0 = A4[(m << 5) + 2*cg], v1 = A4[(m << 5) + 2*cg + 1];
      double uu[4] = {(double)u.x,(double)u.y,(double)u.z,(double)u.w};
      double vv[8] = {(double)v0.x,(double)v0.y,(double)v0.z,(double)v0.w,
                      (double)v1.x,(double)v1.y,(double)v1.z,(double)v1.w};
#pragma unroll
      for (int rr = 0; rr < 4; ++rr)
#pragma unroll
        for (int cc = 0; cc < 8; ++cc)
          acc[rr][cc] = fma(uu[rr], vv[cc], acc[rr][cc]);
    }
    const float4* G4 = (const float4*)Gb;
    for (int d = 0; d < DI; ++d) {
      float4 u  = G4[(d << 5) + rg];
      float4 v0 = G4[(d << 5) + 2*cg], v1 = G4[(d << 5) + 2*cg + 1];
      double uu[4] = {(double)u.x,(double)u.y,(double)u.z,(double)u.w};
      double vv[8] = {(double)v0.x,(double)v0.y,(double)v0.z,(double)v0.w,
                      (double)v1.x,(double)v1.y,(double)v1.z,(double)v1.w};
#pragma unroll
      for (int rr = 0; rr < 4; ++rr)
#pragma unroll
        for (int cc = 0; cc < 8; ++cc)
          acc[rr][cc] = fma(uu[rr], vv[cc], acc[rr][cc]);
    }
#pragma unroll
    for (int rr = 0; rr < 4; ++rr) {
      int ir = 4*rg + rr;
#pragma unroll
      for (int t = 0; t < 4; ++t)
        lds2[ir*ROW2 + 4*cg + t] = make_double2(acc[rr][2*t], acc[rr][2*t+1]);
    }
  }
  __syncthreads();

  // ---------------- Phase 2: f64 sweep of all 128 pivots -> R = -M^{-1} in LDS ----------------
  {
    const int i = tid >> 2, qt = tid & 3;   // row i, 32-col quarter qt
    for (int k = 0; k < NN; ++k) {
      const int kqt = k >> 5, kjj = (k >> 1) & 15, kc = k & 1;
      const double dkk  = ldsd[k*ROWD + k];
      const double rcpd = 1.0 / dkk;              // pivots >= 1 (M >= I)
      const double cv   = ldsd[i*ROWD + k] * rcpd;
      __syncthreads();
      const double2* krow  = lds2 + k*ROW2;
      double2*       myrow = lds2 + i*ROW2;
      double2 rv[16];
      if (i == k) {
#pragma unroll
        for (int jj = 0; jj < 16; ++jj) {
          double2 v = myrow[(qt << 4) | jj];
          v.x *= rcpd; v.y *= rcpd;
          if (jj == kjj && qt == kqt) { if (kc == 0) v.x = -rcpd; else v.y = -rcpd; }
          rv[jj] = v;
        }
      } else {
#pragma unroll
        for (int jj = 0; jj < 16; ++jj) {
          double2 rk = krow[(qt << 4) | jj];
          if (jj == kjj && qt == kqt) { if (kc == 0) rk.x = 0.0; else rk.y = 0.0; }
          double2 ow = myrow[(qt << 4) | jj];
          ow.x = fma(-cv, rk.x, ow.x);
          ow.y = fma(-cv, rk.y, ow.y);
          if (jj == kjj && qt == kqt) { if (kc == 0) ow.x = cv; else ow.y = cv; }
          myrow[(qt << 4) | jj] = ow;
        }
      }
      __syncthreads();
      if (i == k) {
#pragma unroll
        for (int jj = 0; jj < 16; ++jj) myrow[(qt << 4) | jj] = rv[jj];
      }
      __syncthreads();
    }
  }

  // ---------------- Phase 3a: c = q - G^T h - A^T b ----------------
  {
    const int q4 = tid >> 7, i = tid & 127;
    double s = 0;
    for (int j = 24*q4; j < 24*q4 + 24; ++j) {
      double coef = (j < DI) ? ldsd[OFF_HB + j] : ldsd[OFF_BB + j - DI];
      const float* src = (j < DI) ? (Gb + j*NN) : (Ab + (j - DI)*NN);
      s = fma(-(double)src[i], coef, s);
    }
    ldsd[OFF_YB + q4*128 + i] = s;
  }
  __syncthreads();
  if (tid < NN)
    ldsd[OFF_CB + tid] = ldsd[OFF_QBUF + tid] + ldsd[OFF_YB + tid] + ldsd[OFF_YB + 128 + tid]
                       + ldsd[OFF_YB + 256 + tid] + ldsd[OFF_YB + 384 + tid];
  __syncthreads();

  // ---------------- Phase 3b: precompute K (regs), base, qB, u, scalars ----------------
  const int l1 = tid & 127;   // K-dot output row (rows 96..127 compute dummy, stores masked)
  const int mg = tid >> 7;    // 0..3
  float Gr[128];
  {
    const int rowc = (l1 < NZ) ? l1 : 0;
    const float* grow = (rowc < DI) ? (Gb + rowc*NN) : (Ab + (rowc - DI)*NN);
    const float4* g4 = (const float4*)grow;
#pragma unroll
    for (int t = 0; t < 32; ++t) {
      float4 v = g4[t];
      Gr[4*t+0]=v.x; Gr[4*t+1]=v.y; Gr[4*t+2]=v.z; Gr[4*t+3]=v.w;
    }
  }
  double Kc[12], Kc2[12];
  for (int b8 = 0; b8 < 8; ++b8) {
    // 6 sub-rounds: y = R * g_row (2 items each), symmetric-R reads (consecutive lanes)
    for (int sr = 0; sr < 6; ++sr) {
      const int it0 = 12*b8 + 2*sr;
      const float* sA = (it0     < DI) ? (Gb + it0*NN)       : (Ab + (it0 - DI)*NN);
      const float* sB = (it0 + 1 < DI) ? (Gb + (it0+1)*NN)   : (Ab + (it0+1 - DI)*NN);
      const int q4 = tid >> 7, i = tid & 127;
      double a0 = 0, a1 = 0;
#pragma unroll
      for (int tt = 0; tt < 32; ++tt) {
        int t = 32*q4 + tt;
        double rv = ldsd[t*ROWD + i];    // R[t][i] == R[i][t]
        a0 = fma(rv, (double)sA[t], a0);
        a1 = fma(rv, (double)sB[t], a1);
      }
      ldsd[OFF_U3 + (q4*2+0)*128 + i] = a0;
      ldsd[OFF_U3 + (q4*2+1)*128 + i] = a1;
      __syncthreads();
      if (tid < 256) {
        int m = tid >> 7, i2 = tid & 127;
        double y = ldsd[OFF_U3 + (0*2+m)*128 + i2] + ldsd[OFF_U3 + (1*2+m)*128 + i2]
                 + ldsd[OFF_U3 + (2*2+m)*128 + i2] + ldsd[OFF_U3 + (3*2+m)*128 + i2];
        ldsd[OFF_YB + (2*sr+m)*128 + i2] = y;
      }
      __syncthreads();
    }
    // K[:, 12*b8+m] = [G;A] . y_m  (all lanes compute; stores masked)
#pragma unroll
    for (int mi = 0; mi < 3; ++mi) {
      int m = mg + 4*mi;
      double ylo = ldsd[OFF_YB + m*128 + l];
      double yhi = ldsd[OFF_YB + m*128 + 64 + l];
      double kv = dot128(Gr, ylo, yhi);
      if (l1 < NZ) ldsd[OFF_U3 + m*NZ + l1] = kv;
    }
    __syncthreads();
    if (w == b8) {
#pragma unroll
      for (int j = 0; j < 12; ++j) {
        Kc[j]  = ldsd[OFF_U3 + j*NZ + l];
        Kc2[j] = ldsd[OFF_U3 + j*NZ + 64 + (l & 31)];
      }
    }
    __syncthreads();
  }
  // items c, q: u = Rc, base = B^T u, qB = B^T Rq, scalars
  {
    const int q4 = tid >> 7, i = tid & 127;
    double a0 = 0, a1 = 0;
#pragma unroll
    for (int tt = 0; tt < 32; ++tt) {
      int t = 32*q4 + tt;
      double rv = ldsd[t*ROWD + i];
      a0 = fma(rv, ldsd[OFF_CB + t], a0);
      a1 = fma(rv, ldsd[OFF_QBUF + t], a1);
    }
    ldsd[OFF_U3 + (q4*2+0)*128 + i] = a0;
    ldsd[OFF_U3 + (q4*2+1)*128 + i] = a1;
  }
  __syncthreads();
  if (tid < 256) {
    int m = tid >> 7, i2 = tid & 127;
    double y = ldsd[OFF_U3 + (0*2+m)*128 + i2] + ldsd[OFF_U3 + (1*2+m)*128 + i2]
             + ldsd[OFF_U3 + (2*2+m)*128 + i2] + ldsd[OFF_U3 + (3*2+m)*128 + i2];
    ldsd[OFF_YB + m*128 + i2] = y;
  }
  __syncthreads();
  if (tid < NN) ldsd[OFF_UB + tid] = ldsd[OFF_YB + tid];   // u = R c
  {
    double ylo0 = ldsd[OFF_YB + l],        yhi0 = ldsd[OFF_YB + 64 + l];
    double ylo1 = ldsd[OFF_YB + 128 + l],  yhi1 = ldsd[OFF_YB + 192 + l];
    double kb = dot128(Gr, ylo0, yhi0);    // base row
    double kq = dot128(Gr, ylo1, yhi1);    // qB row
    if (mg == 0 && l1 < NZ) { ldsd[OFF_U3 + l1] = kb; ldsd[OFF_U3 + NZ + l1] = kq; }
  }
  __syncthreads();
  if (tid < NZ) {
    ldsd[OFF_BASE + tid] = ldsd[OFF_U3 + tid];
    ldsd[OFF_QBV  + tid] = ldsd[OFF_U3 + NZ + tid];
    ldsd[OFF_ZB   + tid] = 0.0;
  }
  if (w == 0) {
    double pc = ldsd[OFF_UB + l]*ldsd[OFF_CB + l]   + ldsd[OFF_UB + 64 + l]*ldsd[OFF_CB + 64 + l];
    double pq = ldsd[OFF_UB + l]*ldsd[OFF_QBUF + l] + ldsd[OFF_UB + 64 + l]*ldsd[OFF_QBUF + 64 + l];
#pragma unroll
    for (int off = 32; off >= 1; off >>= 1) { pc += __shfl_xor(pc, off); pq += __shfl_xor(pq, off); }
    if (l == 0) { ldsd[OFF_CST + 0] = pc; ldsd[OFF_CST + 1] = pq; }
  }
  __syncthreads();

  // ---------------- Phase 3c: ADMM iteration on z (96), 2 barriers/iter ----------------
  const double S_uc = ldsd[OFF_CST + 0], S_qu = ldsd[OFF_CST + 1];
  double nu_r = 0, lam_r = 0, h_r = 0, b_r = 0, bl0 = 0, bl1 = 0, bq0 = 0, bq1 = 0;
  if (w == 0) {
    h_r = ldsd[OFF_HB + l];
    bl0 = ldsd[OFF_BASE + l];           bq0 = ldsd[OFF_QBV + l];
    bl1 = ldsd[OFF_BASE + 64 + (l & 31)];
  }
  if (w == 1 && l < ME) {
    b_r = ldsd[OFF_BB + l];
    bl1 = ldsd[OFF_BASE + 64 + l];      bq1 = ldsd[OFF_QBV + 64 + l];
  }
  double res_prev = 1000.0, res_cur = -100.0;
  double zlo = 0.0, zhi = 0.0;
  const int jbase = 12 * w;

  for (int it = 0; it < MAXIT; ++it) {
    zlo = ldsd[OFF_ZB + l];              // z[l]          (all lanes: readlane sources)
    zhi = ldsd[OFF_ZB + 64 + (l & 31)];  // z[64+(l&31)]
    double a0 = (w == 0) ? bl0 : 0.0;    // y rows 0..63 partial (j-chunk of this wave)
    double a1 = (w == 0) ? bl1 : 0.0;    // y rows 64..95 partial
#pragma unroll
    for (int j2 = 0; j2 < 12; ++j2) {
      int j = jbase + j2;
      double zj = (j < 64) ? rld(zlo, j) : rld(zhi, j & 31);
      a0 = fma(Kc[j2],  zj, a0);
      a1 = fma(Kc2[j2], zj, a1);
    }
    ldsd[OFF_U3 + w*NZ + l] = a0;
    if (l < 32) ldsd[OFF_U3 + w*NZ + 64 + l] = a1;
    __syncthreads();
    if (w == 0) {
      double Gx = 0;
#pragma unroll
      for (int ww = 0; ww < 8; ++ww) Gx += ldsd[OFF_U3 + ww*NZ + l];
      double sk = fmax(0.0, -nu_r - Gx + h_r);
      nu_r = nu_r + Gx + sk - h_r;
      ldsd[OFF_ZB + l] = nu_r + sk;
      double t = -0.5*(zlo*(bl0 + Gx) + Gx*Gx) + bq0*zlo;
#pragma unroll
      for (int off = 32; off >= 1; off >>= 1) t += __shfl_xor(t, off);
      if (l == 0) ldsd[OFF_CST + 2] = t;
    } else if (w == 1) {
      double t = 0.0;
      if (l < ME) {
        double Ax = 0;
#pragma unroll
        for (int ww = 0; ww < 8; ++ww) Ax += ldsd[OFF_U3 + ww*NZ + 64 + l];
        lam_r = lam_r + Ax - b_r;
        ldsd[OFF_ZB + 64 + l] = lam_r;
        t = -0.5*(zhi*(bl1 + Ax) + Ax*Ax) + bq1*zhi;
      }
#pragma unroll
      for (int off = 32; off >= 1; off >>= 1) t += __shfl_xor(t, off);
      if (l == 0) ldsd[OFF_CST + 3] = t;
    }
    __syncthreads();
    double obj = ldsd[OFF_CST + 2] + ldsd[OFF_CST + 3] - 0.5*S_uc + S_qu;
    res_prev = res_cur; res_cur = obj;
    double rel = fabs((res_cur - res_prev) / res_prev);
    if (rel <= 1e-5) break;   // uniform across threads (identical f64 recurrence)
  }

  // ---------------- Phase 3d: final x = R (c + B z)  with z = z at top of stopping iteration ----
  {
    const int q4 = tid >> 7, i = tid & 127;
    double s = 0;
    for (int j = 24*q4; j < 24*q4 + 24; ++j) {
      double zj = (j < 64) ? rld(zlo, j) : rld(zhi, j & 31);
      const float* src = (j < DI) ? (Gb + j*NN) : (Ab + (j - DI)*NN);
      s = fma((double)src[i], zj, s);
    }
    ldsd[OFF_YB + q4*128 + i] = s;
  }
  __syncthreads();
  if (tid < NN)
    ldsd[OFF_UB + tid] = ldsd[OFF_CB + tid] + ldsd[OFF_YB + tid] + ldsd[OFF_YB + 128 + tid]
                       + ldsd[OFF_YB + 256 + tid] + ldsd[OFF_YB + 384 + tid];
  __syncthreads();
  {
    const int q4 = tid >> 7, i = tid & 127;
    double s = 0;
#pragma unroll
    for (int tt = 0; tt < 32; ++tt) {
      int t = 32*q4 + tt;
      s = fma(ldsd[t*ROWD + i], ldsd[OFF_UB + t], s);
    }
    ldsd[OFF_YB + 512 + q4*128 + i] = s;
  }
  __syncthreads();
  if (tid < NN) {
    double x = ldsd[OFF_YB + 512 + tid] + ldsd[OFF_YB + 640 + tid]
             + ldsd[OFF_YB + 768 + tid] + ldsd[OFF_YB + 896 + tid];
    out[(size_t)bidx * NN + tid] = (float)x;
  }
}

extern "C" void kernel_launch(void* const* d_in, const int* in_sizes, int n_in,
                              void* d_out, int out_size, void* d_ws, size_t ws_size,
                              hipStream_t stream) {
  (void)in_sizes; (void)n_in; (void)out_size; (void)d_ws; (void)ws_size;
  const float* Q = (const float*)d_in[0];
  const float* q = (const float*)d_in[1];
  const float* G = (const float*)d_in[2];
  const float* h = (const float*)d_in[3];
  const float* A = (const float*)d_in[4];
  const float* b = (const float*)d_in[5];
  float* out = (float*)d_out;
  const size_t lds_bytes = (size_t)LDS_DBL * sizeof(double);  // 160832 <= 163840
  altdiff_kernel<<<dim3(64), dim3(512), lds_bytes, stream>>>(Q, q, G, h, A, b, out);
}

// Round 5
// 2015.048 us; speedup vs baseline: 1.1602x; 1.1602x over previous
//
#include <hip/hip_runtime.h>

#define NN 128
#define ME 32
#define DI 64
#define NZ 96
#define ROWD 130
#define ROW2 65
#define MAXIT 5000

// ---- LDS layout (double offsets). R: [0, 16640). Total 19944 dbl = 159552 B.
#define OFF_UN 16640
#define ZB    (OFF_UN)           // [96] z (loop)
#define PLO   (OFF_UN + 96)      // [64][5] lo partials (loop)
#define PHI   (OFF_UN + 416)     // [32][5] hi partials (loop)
#define OBJP  (OFF_UN + 576)     // [2] obj partials (loop)
#define YBUF  (OFF_UN)           // [128][12] Y block (stage 2)
#define KBUF  (OFF_UN + 1536)    // [12][96] K cols (stage 2)
#define CPART (OFF_UN + 1024)    // [2][128] (stage 3a) / FPART (final)
#define VP    (OFF_UN + 1280)    // [4][128] (stage 3b)
#define BASEV (OFF_UN + 1792)    // [96]
#define QBV   (OFF_UN + 1888)    // [96]
#define FPART (OFF_UN + 1024)    // [2][128] (final)
#define RHSV  (OFF_UN + 1280)    // [128] (final)
#define XPART (OFF_UN + 1408)    // [2][128] (final)
#define CB    (OFF_UN + 2688)    // [128] c
#define QBUF  (OFF_UN + 2816)    // [128] q
#define V1    (OFF_UN + 2944)    // [128] Rc
#define V2    (OFF_UN + 3072)    // [128] Rq
#define HB    (OFF_UN + 3200)    // [64]
#define BB    (OFF_UN + 3264)    // [32]
#define CST   (OFF_UN + 3296)    // [8]: 0=u.c 1=q.u
#define LDS_DBL (OFF_UN + 3304)  // 19944

// SGPR broadcast. CONTRACT: source computed by ALL 64 lanes (no divergence upstream).
__device__ __forceinline__ double rld(double v, int lane) {
  union { double d; unsigned long long u; } c; c.d = v;
  unsigned lo = (unsigned)c.u, hi = (unsigned)(c.u >> 32);
  lo = (unsigned)__builtin_amdgcn_readlane((int)lo, lane);
  hi = (unsigned)__builtin_amdgcn_readlane((int)hi, lane);
  c.u = (((unsigned long long)hi) << 32) | lo;
  return c.d;
}

__global__ __launch_bounds__(256, 1) void altdiff_kernel(
    const float* __restrict__ Qg, const float* __restrict__ qg,
    const float* __restrict__ Gg, const float* __restrict__ hg,
    const float* __restrict__ Ag, const float* __restrict__ bg,
    float* __restrict__ out)
{
  extern __shared__ double ldsd[];
  double2* lds2 = (double2*)ldsd;

  const int bidx = blockIdx.x;
  const int tid  = threadIdx.x;
  const int w    = tid >> 6;     // wave 0..3
  const int l    = tid & 63;     // lane
  const int ia   = tid & 127;    // 128-split index
  const int hh   = tid >> 7;     // 0..1 (wave-uniform)

  const float* Qb = Qg + (size_t)bidx * NN * NN;
  const float* Ab = Ag + (size_t)bidx * ME * NN;
  const float* Gb = Gg + (size_t)bidx * DI * NN;
  const float* qb = qg + (size_t)bidx * NN;
  const float* hb = hg + (size_t)bidx * DI;
  const float* bv = bg + (size_t)bidx * ME;

  // stage h, b, q (f64)
  if (tid < DI) ldsd[HB + tid] = (double)hb[tid];
  else if (tid < DI + ME) ldsd[BB + tid - DI] = (double)bv[tid - DI];
  if (tid >= 128) ldsd[QBUF + tid - 128] = (double)qb[tid - 128];

  // ---------------- Phase 1: M = Q + A^T A + G^T G (f64) -> LDS rows of 130 dbl ----------------
  {
    const int r = tid >> 4, c = tid & 15;   // 8x8 tile at rows 8r.., cols 8c..
    double acc[8][8];
    const float4* Q4 = (const float4*)Qb;
#pragma unroll
    for (int rr = 0; rr < 8; ++rr) {
      float4 q0 = Q4[((8*r+rr) << 5) + 2*c];
      float4 q1 = Q4[((8*r+rr) << 5) + 2*c + 1];
      acc[rr][0]=(double)q0.x; acc[rr][1]=(double)q0.y; acc[rr][2]=(double)q0.z; acc[rr][3]=(double)q0.w;
      acc[rr][4]=(double)q1.x; acc[rr][5]=(double)q1.y; acc[rr][6]=(double)q1.z; acc[rr][7]=(double)q1.w;
    }
    const float4* A4 = (const float4*)Ab;
    for (int m = 0; m < ME; ++m) {
      float4 u0 = A4[(m << 5) + 2*r], u1 = A4[(m << 5) + 2*r + 1];
      float4 v0 = A4[(m << 5) + 2*c], v1 = A4[(m << 5) + 2*c + 1];
      double uu[8] = {(double)u0.x,(double)u0.y,(double)u0.z,(double)u0.w,
                      (double)u1.x,(double)u1.y,(double)u1.z,(double)u1.w};
      double vv[8] = {(double)v0.x,(double)v0.y,(double)v0.z,(double)v0.w,
                      (double)v1.x,(double)v1.y,(double)v1.z,(double)v1.w};
#pragma unroll
      for (int rr = 0; rr < 8; ++rr)
#pragma unroll
        for (int cc = 0; cc < 8; ++cc)
          acc[rr][cc] = fma(uu[rr], vv[cc], acc[rr][cc]);
    }
    const float4* G4 = (const float4*)Gb;
    for (int d = 0; d < DI; ++d) {
      float4 u0 = G4[(d << 5) + 2*r], u1 = G4[(d << 5) + 2*r + 1];
      float4 v0 = G4[(d << 5) + 2*c], v1 = G4[(d << 5) + 2*c + 1];
      double uu[8] = {(double)u0.x,(double)u0.y,(double)u0.z,(double)u0.w,
                      (double)u1.x,(double)u1.y,(double)u1.z,(double)u1.w};
      double vv[8] = {(double)v0.x,(double)v0.y,(double)v0.z,(double)v0.w,
                      (double)v1.x,(double)v1.y,(double)v1.z,(double)v1.w};
#pragma unroll
      for (int rr = 0; rr < 8; ++rr)
#pragma unroll
        for (int cc = 0; cc < 8; ++cc)
          acc[rr][cc] = fma(uu[rr], vv[cc], acc[rr][cc]);
    }
#pragma unroll
    for (int rr = 0; rr < 8; ++rr) {
      int ir = 8*r + rr;
#pragma unroll
      for (int t = 0; t < 4; ++t)
        lds2[ir*ROW2 + 4*c + t] = make_double2(acc[rr][2*t], acc[rr][2*t+1]);
    }
  }
  __syncthreads();

  // ---------------- Phase 2: f64 sweep of all 128 pivots -> R = -M^{-1} (validated R3 code) ----
  {
    const int i = tid >> 1, h = tid & 1;
    for (int k = 0; k < NN; ++k) {
      const int kh = k >> 6, kg = (k >> 1) & 31, kc = k & 1;
      const double dkk  = ldsd[k*ROWD + k];
      const double rcpd = 1.0 / dkk;              // pivots >= 1 (M >= I)
      const double cv   = ldsd[i*ROWD + k] * rcpd;
      __syncthreads();
      const double2* krow  = lds2 + k*ROW2;
      double2*       myrow = lds2 + i*ROW2;
      double2 rv[32];
      if (i == k) {
#pragma unroll
        for (int jj = 0; jj < 32; ++jj) {
          double2 v = myrow[(h << 5) | jj];
          v.x *= rcpd; v.y *= rcpd;
          if (jj == kg && h == kh) { if (kc == 0) v.x = -rcpd; else v.y = -rcpd; }
          rv[jj] = v;
        }
      } else {
#pragma unroll
        for (int jj = 0; jj < 32; ++jj) {
          double2 rk = krow[(h << 5) | jj];
          if (jj == kg && h == kh) { if (kc == 0) rk.x = 0.0; else rk.y = 0.0; }
          double2 ow = myrow[(h << 5) | jj];
          ow.x = fma(-cv, rk.x, ow.x);
          ow.y = fma(-cv, rk.y, ow.y);
          if (jj == kg && h == kh) { if (kc == 0) ow.x = cv; else ow.y = cv; }
          myrow[(h << 5) | jj] = ow;
        }
      }
      __syncthreads();
      if (i == k) {
#pragma unroll
        for (int jj = 0; jj < 32; ++jj) myrow[(h << 5) | jj] = rv[jj];
      }
      __syncthreads();
    }
  }

  // ---------------- Stage 2: K = B (R B^T) in 8 blocks of 12 cols; conflict-free reads --------
  double Kc[24], Kc2[24];
  for (int blk = 0; blk < 8; ++blk) {
    // (a) Y[:, 12 cols] = R * g  (R[t][ia]: lane-consecutive -> conflict-free; R symmetric)
    {
      const float* gp[6];
#pragma unroll
      for (int jj = 0; jj < 6; ++jj) {
        int it = 12*blk + 6*hh + jj;
        gp[jj] = (it < DI) ? (Gb + it*NN) : (Ab + (it - DI)*NN);
      }
      double acc[6] = {0,0,0,0,0,0};
#pragma unroll 4
      for (int t = 0; t < NN; ++t) {
        double rv = ldsd[t*ROWD + ia];
#pragma unroll
        for (int jj = 0; jj < 6; ++jj)
          acc[jj] = fma(rv, (double)gp[jj][t], acc[jj]);
      }
      double2* yst = (double2*)(ldsd + YBUF + ia*12 + 6*hh);
#pragma unroll
      for (int p = 0; p < 3; ++p) yst[p] = make_double2(acc[2*p], acc[2*p+1]);
    }
    __syncthreads();
    // (b) K rows: Y reads wave-uniform (broadcast), B rows global
    {
      const int r2 = (ia < NZ) ? ia : 0;
      const float* brow = (r2 < DI) ? (Gb + r2*NN) : (Ab + (r2 - DI)*NN);
      double acc[6] = {0,0,0,0,0,0};
#pragma unroll 4
      for (int t = 0; t < NN; ++t) {
        double bvv = (double)brow[t];
        const double2* yr = (const double2*)(ldsd + YBUF + t*12 + 6*hh);
        double2 y0 = yr[0], y1 = yr[1], y2 = yr[2];
        acc[0] = fma(bvv, y0.x, acc[0]); acc[1] = fma(bvv, y0.y, acc[1]);
        acc[2] = fma(bvv, y1.x, acc[2]); acc[3] = fma(bvv, y1.y, acc[3]);
        acc[4] = fma(bvv, y2.x, acc[4]); acc[5] = fma(bvv, y2.y, acc[5]);
      }
      if (ia < NZ) {
#pragma unroll
        for (int jj = 0; jj < 6; ++jj) ldsd[KBUF + (6*hh + jj)*NZ + ia] = acc[jj];
      }
    }
    __syncthreads();
    if (w == (blk >> 1)) {
      const int off = 12 * (blk & 1);
#pragma unroll
      for (int jj = 0; jj < 12; ++jj) {
        Kc [off+jj] = ldsd[KBUF + jj*NZ + l];
        Kc2[off+jj] = ldsd[KBUF + jj*NZ + 64 + (l & 31)];
      }
    }
    __syncthreads();
  }

  // ---------------- Stage 3a: c = q - G^T h - A^T b ----------------
  {
    double s = 0;
#pragma unroll 8
    for (int jc = 0; jc < 48; ++jc) {
      int j = 48*hh + jc;
      double coef = (j < DI) ? ldsd[HB + j] : ldsd[BB + j - DI];
      const float* src = (j < DI) ? (Gb + j*NN) : (Ab + (j - DI)*NN);
      s = fma(-(double)src[ia], coef, s);
    }
    ldsd[CPART + hh*128 + ia] = s;
  }
  __syncthreads();
  if (tid < NN) ldsd[CB + tid] = ldsd[QBUF + tid] + ldsd[CPART + tid] + ldsd[CPART + 128 + tid];
  __syncthreads();

  // ---------------- Stage 3b: v1 = R c, v2 = R q ----------------
  {
    double a = 0, b2 = 0;
#pragma unroll 4
    for (int tt = 0; tt < 64; ++tt) {
      int t = 64*hh + tt;
      double rv = ldsd[t*ROWD + ia];
      a  = fma(rv, ldsd[CB + t], a);
      b2 = fma(rv, ldsd[QBUF + t], b2);
    }
    ldsd[VP + hh*128 + ia] = a;
    ldsd[VP + 256 + hh*128 + ia] = b2;
  }
  __syncthreads();
  if (tid < NN) {
    ldsd[V1 + tid] = ldsd[VP + tid] + ldsd[VP + 128 + tid];
    ldsd[V2 + tid] = ldsd[VP + 256 + tid] + ldsd[VP + 384 + tid];
  }
  __syncthreads();

  // ---------------- Stage 3c: base = B v1, qB = B v2, scalars, z init ----------------
  {
    const int r2 = (ia < NZ) ? ia : 0;
    const float* brow = (r2 < DI) ? (Gb + r2*NN) : (Ab + (r2 - DI)*NN);
    const int voff = hh ? V2 : V1;
    double s = 0;
#pragma unroll 4
    for (int t = 0; t < NN; ++t) s = fma((double)brow[t], ldsd[voff + t], s);
    if (ia < NZ) ldsd[(hh ? QBV : BASEV) + ia] = s;
  }
  if (w == 0) {
    double pc = ldsd[V1+l]*ldsd[CB+l]   + ldsd[V1+64+l]*ldsd[CB+64+l];
    double pq = ldsd[V1+l]*ldsd[QBUF+l] + ldsd[V1+64+l]*ldsd[QBUF+64+l];
#pragma unroll
    for (int off = 32; off >= 1; off >>= 1) { pc += __shfl_xor(pc, off); pq += __shfl_xor(pq, off); }
    if (l == 0) { ldsd[CST] = pc; ldsd[CST+1] = pq; }
  }
  if (tid < NZ) ldsd[ZB + tid] = 0.0;
  __syncthreads();

  // per-wave loop registers
  double bAr = 0, bBr = 0, qAr = 0, h_r = 0, b_r = 0;
  if (w == 0)      { bAr = ldsd[BASEV + l]; bBr = ldsd[BASEV + 64 + (l&31)]; h_r = ldsd[HB + l]; }
  else if (w == 1) { b_r = ldsd[BB + (l & 31)]; }
  else if (w == 2) { bAr = ldsd[BASEV + l]; qAr = ldsd[QBV + l]; }
  else             { bBr = ldsd[BASEV + 64 + (l&31)]; qAr = ldsd[QBV + 64 + (l&31)]; }
  const double S_uc = ldsd[CST], S_qu = ldsd[CST + 1];
  double nu_r = 0, lam_r = 0;
  double res_prev = 1000.0, res_cur = -100.0;
  double zlo = 0.0, zhi = 0.0;

  // ---------------- ADMM loop on z (96-dim), 2 barriers/iter ----------------
  for (int it = 0; it < MAXIT; ++it) {
    zlo = ldsd[ZB + l];
    zhi = ldsd[ZB + 64 + (l & 31)];
    double a0, a1;
    if (w == 0) {
      a0 = bAr; a1 = bBr;     // base seeded once (wave 0)
#pragma unroll
      for (int j = 0; j < 24; ++j) {
        double zj = rld(zlo, j);
        a0 = fma(Kc[j], zj, a0); a1 = fma(Kc2[j], zj, a1);
      }
    } else if (w == 1) {
      a0 = 0; a1 = 0;
#pragma unroll
      for (int j = 0; j < 24; ++j) {
        double zj = rld(zlo, 24 + j);
        a0 = fma(Kc[j], zj, a0); a1 = fma(Kc2[j], zj, a1);
      }
    } else if (w == 2) {
      a0 = 0; a1 = 0;
#pragma unroll
      for (int j = 0; j < 16; ++j) {
        double zj = rld(zlo, 48 + j);
        a0 = fma(Kc[j], zj, a0); a1 = fma(Kc2[j], zj, a1);
      }
#pragma unroll
      for (int j = 0; j < 8; ++j) {
        double zj = rld(zhi, j);
        a0 = fma(Kc[16+j], zj, a0); a1 = fma(Kc2[16+j], zj, a1);
      }
    } else {
      a0 = 0; a1 = 0;
#pragma unroll
      for (int j = 0; j < 24; ++j) {
        double zj = rld(zhi, 8 + j);
        a0 = fma(Kc[j], zj, a0); a1 = fma(Kc2[j], zj, a1);
      }
    }
    ldsd[PLO + l*5 + w] = a0;
    if (l < 32) ldsd[PHI + l*5 + w] = a1;
    __syncthreads();
    if (w == 0) {
      const int p0 = PLO + l*5;
      double y = (ldsd[p0] + ldsd[p0+1]) + (ldsd[p0+2] + ldsd[p0+3]);
      double sk = fmax(0.0, -nu_r - y + h_r);
      nu_r = nu_r + y + sk - h_r;
      ldsd[ZB + l] = nu_r + sk;
    } else if (w == 1) {
      const int p0 = PHI + (l & 31)*5;
      double ym = (ldsd[p0] + ldsd[p0+1]) + (ldsd[p0+2] + ldsd[p0+3]);
      lam_r = lam_r + ym - b_r;
      if (l < 32) ldsd[ZB + 64 + l] = lam_r;
    } else if (w == 2) {
      const int p0 = PLO + l*5;
      double y = (ldsd[p0] + ldsd[p0+1]) + (ldsd[p0+2] + ldsd[p0+3]);
      double tv = fma(qAr, zlo, -0.5*(zlo*(bAr + y) + y*y));
#pragma unroll
      for (int off = 32; off >= 1; off >>= 1) tv += __shfl_xor(tv, off);
      if (l == 0) ldsd[OBJP] = tv;
    } else {
      const int p0 = PHI + (l & 31)*5;
      double ym = (ldsd[p0] + ldsd[p0+1]) + (ldsd[p0+2] + ldsd[p0+3]);
      double tv = (l < 32) ? fma(qAr, zhi, -0.5*(zhi*(bBr + ym) + ym*ym)) : 0.0;
#pragma unroll
      for (int off = 32; off >= 1; off >>= 1) tv += __shfl_xor(tv, off);
      if (l == 0) ldsd[OBJP + 1] = tv;
    }
    __syncthreads();
    double obj = ldsd[OBJP] + ldsd[OBJP + 1] - 0.5*S_uc + S_qu;
    res_prev = res_cur; res_cur = obj;
    if (fabs((res_cur - res_prev) / res_prev) <= 1e-5) break;  // uniform (replicated f64)
  }

  // ---------------- Final: x = R (c + B^T z), z = top-of-stopping-iteration ----------------
  __syncthreads();
  {
    double s = 0;
#pragma unroll 8
    for (int jc = 0; jc < 48; ++jc) {
      int j = 48*hh + jc;
      double zj = (j < 64) ? rld(zlo, j) : rld(zhi, j - 64);
      const float* src = (j < DI) ? (Gb + j*NN) : (Ab + (j - DI)*NN);
      s = fma((double)src[ia], zj, s);
    }
    ldsd[FPART + hh*128 + ia] = s;
  }
  __syncthreads();
  if (tid < NN) ldsd[RHSV + tid] = ldsd[CB + tid] + ldsd[FPART + tid] + ldsd[FPART + 128 + tid];
  __syncthreads();
  {
    double s = 0;
#pragma unroll 4
    for (int tt = 0; tt < 64; ++tt) {
      int t = 64*hh + tt;
      s = fma(ldsd[t*ROWD + ia], ldsd[RHSV + t], s);   // R[t][ia] = R[ia][t], conflict-free
    }
    ldsd[XPART + hh*128 + ia] = s;
  }
  __syncthreads();
  if (tid < NN)
    out[(size_t)bidx * NN + tid] = (float)(ldsd[XPART + tid] + ldsd[XPART + 128 + tid]);
}

extern "C" void kernel_launch(void* const* d_in, const int* in_sizes, int n_in,
                              void* d_out, int out_size, void* d_ws, size_t ws_size,
                              hipStream_t stream) {
  (void)in_sizes; (void)n_in; (void)out_size; (void)d_ws; (void)ws_size;
  const float* Q = (const float*)d_in[0];
  const float* q = (const float*)d_in[1];
  const float* G = (const float*)d_in[2];
  const float* h = (const float*)d_in[3];
  const float* A = (const float*)d_in[4];
  const float* b = (const float*)d_in[5];
  float* out = (float*)d_out;
  const size_t lds_bytes = (size_t)LDS_DBL * sizeof(double);  // 159552
  altdiff_kernel<<<dim3(64), dim3(256), lds_bytes, stream>>>(Q, q, G, h, A, b, out);
}

// Round 6
// 1104.994 us; speedup vs baseline: 2.1157x; 1.8236x over previous
//
#include <hip/hip_runtime.h>

#define NN 128
#define ME 32
#define DI 64
#define NZ 96
#define ROWD 130
#define ROW2 65
#define MAXIT 5000

// ---- LDS layout (double offsets). R: [0, 16640). Total 19944 dbl = 159552 B.
#define OFF_UN 16640
#define ZB    (OFF_UN)           // [96] z (loop)
#define PLO   (OFF_UN + 96)      // [4][64] lo partials (loop)
#define PHI   (OFF_UN + 352)     // [4][32] hi partials (loop)
#define OBJP  (OFF_UN + 480)     // [2] obj partials (loop)
#define YBUF  (OFF_UN)           // [128][12] Y block (stage 2, dead before loop)
#define KBUF  (OFF_UN + 1536)    // [12][96] K cols (stage 2, dead before loop)
#define CPART (OFF_UN + 1024)    // [2][128] (stage 3a)
#define VP    (OFF_UN + 1280)    // [4][128] (stage 3b)
#define BASEV (OFF_UN + 1792)    // [96] (persists through loop)
#define QBV   (OFF_UN + 1888)    // [96] (persists through loop)
#define FPART (OFF_UN + 1024)    // [2][128] (final)
#define RHSV  (OFF_UN + 1280)    // [128] (final)
#define XPART (OFF_UN + 1408)    // [2][128] (final)
#define CB    (OFF_UN + 2688)    // [128] c
#define QBUF  (OFF_UN + 2816)    // [128] q
#define V1    (OFF_UN + 2944)    // [128] Rc
#define V2    (OFF_UN + 3072)    // [128] Rq
#define HB    (OFF_UN + 3200)    // [64]
#define BB    (OFF_UN + 3264)    // [32]
#define CST   (OFF_UN + 3296)    // [8]: 0=u.c 1=q.u
#define LDS_DBL (OFF_UN + 3304)  // 19944

// SGPR broadcast. CONTRACT: source computed by ALL 64 lanes (no divergence upstream).
__device__ __forceinline__ double rld(double v, int lane) {
  union { double d; unsigned long long u; } c; c.d = v;
  unsigned lo = (unsigned)c.u, hi = (unsigned)(c.u >> 32);
  lo = (unsigned)__builtin_amdgcn_readlane((int)lo, lane);
  hi = (unsigned)__builtin_amdgcn_readlane((int)hi, lane);
  c.u = (((unsigned long long)hi) << 32) | lo;
  return c.d;
}

__global__ __launch_bounds__(256, 1) void altdiff_kernel(
    const float* __restrict__ Qg, const float* __restrict__ qg,
    const float* __restrict__ Gg, const float* __restrict__ hg,
    const float* __restrict__ Ag, const float* __restrict__ bg,
    float* __restrict__ out)
{
  extern __shared__ double ldsd[];
  double2* lds2 = (double2*)ldsd;

  const int bidx = blockIdx.x;
  const int tid  = threadIdx.x;
  const int w    = tid >> 6;     // wave 0..3
  const int l    = tid & 63;     // lane
  const int ia   = tid & 127;    // 128-split index
  const int hh   = tid >> 7;     // 0..1 (wave-uniform)

  const float* Qb = Qg + (size_t)bidx * NN * NN;
  const float* Ab = Ag + (size_t)bidx * ME * NN;
  const float* Gb = Gg + (size_t)bidx * DI * NN;
  const float* qb = qg + (size_t)bidx * NN;
  const float* hb = hg + (size_t)bidx * DI;
  const float* bv = bg + (size_t)bidx * ME;

  // stage h, b, q (f64)
  if (tid < DI) ldsd[HB + tid] = (double)hb[tid];
  else if (tid < DI + ME) ldsd[BB + tid - DI] = (double)bv[tid - DI];
  if (tid >= 128) ldsd[QBUF + tid - 128] = (double)qb[tid - 128];

  // ---------------- Phase 1: M = Q + A^T A + G^T G (f64) -> LDS rows of 130 dbl ----------------
  {
    const int r = tid >> 4, c = tid & 15;   // 8x8 tile at rows 8r.., cols 8c..
    double acc[8][8];
    const float4* Q4 = (const float4*)Qb;
#pragma unroll
    for (int rr = 0; rr < 8; ++rr) {
      float4 q0 = Q4[((8*r+rr) << 5) + 2*c];
      float4 q1 = Q4[((8*r+rr) << 5) + 2*c + 1];
      acc[rr][0]=(double)q0.x; acc[rr][1]=(double)q0.y; acc[rr][2]=(double)q0.z; acc[rr][3]=(double)q0.w;
      acc[rr][4]=(double)q1.x; acc[rr][5]=(double)q1.y; acc[rr][6]=(double)q1.z; acc[rr][7]=(double)q1.w;
    }
    const float4* A4 = (const float4*)Ab;
    for (int m = 0; m < ME; ++m) {
      float4 u0 = A4[(m << 5) + 2*r], u1 = A4[(m << 5) + 2*r + 1];
      float4 v0 = A4[(m << 5) + 2*c], v1 = A4[(m << 5) + 2*c + 1];
      double uu[8] = {(double)u0.x,(double)u0.y,(double)u0.z,(double)u0.w,
                      (double)u1.x,(double)u1.y,(double)u1.z,(double)u1.w};
      double vv[8] = {(double)v0.x,(double)v0.y,(double)v0.z,(double)v0.w,
                      (double)v1.x,(double)v1.y,(double)v1.z,(double)v1.w};
#pragma unroll
      for (int rr = 0; rr < 8; ++rr)
#pragma unroll
        for (int cc = 0; cc < 8; ++cc)
          acc[rr][cc] = fma(uu[rr], vv[cc], acc[rr][cc]);
    }
    const float4* G4 = (const float4*)Gb;
    for (int d = 0; d < DI; ++d) {
      float4 u0 = G4[(d << 5) + 2*r], u1 = G4[(d << 5) + 2*r + 1];
      float4 v0 = G4[(d << 5) + 2*c], v1 = G4[(d << 5) + 2*c + 1];
      double uu[8] = {(double)u0.x,(double)u0.y,(double)u0.z,(double)u0.w,
                      (double)u1.x,(double)u1.y,(double)u1.z,(double)u1.w};
      double vv[8] = {(double)v0.x,(double)v0.y,(double)v0.z,(double)v0.w,
                      (double)v1.x,(double)v1.y,(double)v1.z,(double)v1.w};
#pragma unroll
      for (int rr = 0; rr < 8; ++rr)
#pragma unroll
        for (int cc = 0; cc < 8; ++cc)
          acc[rr][cc] = fma(uu[rr], vv[cc], acc[rr][cc]);
    }
#pragma unroll
    for (int rr = 0; rr < 8; ++rr) {
      int ir = 8*r + rr;
#pragma unroll
      for (int t = 0; t < 4; ++t)
        lds2[ir*ROW2 + 4*c + t] = make_double2(acc[rr][2*t], acc[rr][2*t+1]);
    }
  }
  __syncthreads();

  // ---------------- Phase 2: f64 sweep of all 128 pivots -> R = -M^{-1} (validated) ----------
  {
    const int i = tid >> 1, h = tid & 1;
    for (int k = 0; k < NN; ++k) {
      const int kh = k >> 6, kg = (k >> 1) & 31, kc = k & 1;
      const double dkk  = ldsd[k*ROWD + k];
      const double rcpd = 1.0 / dkk;              // pivots >= 1 (M >= I)
      const double cv   = ldsd[i*ROWD + k] * rcpd;
      __syncthreads();
      const double2* krow  = lds2 + k*ROW2;
      double2*       myrow = lds2 + i*ROW2;
      double2 rv[32];
      if (i == k) {
#pragma unroll
        for (int jj = 0; jj < 32; ++jj) {
          double2 v = myrow[(h << 5) | jj];
          v.x *= rcpd; v.y *= rcpd;
          if (jj == kg && h == kh) { if (kc == 0) v.x = -rcpd; else v.y = -rcpd; }
          rv[jj] = v;
        }
      } else {
#pragma unroll
        for (int jj = 0; jj < 32; ++jj) {
          double2 rk = krow[(h << 5) | jj];
          if (jj == kg && h == kh) { if (kc == 0) rk.x = 0.0; else rk.y = 0.0; }
          double2 ow = myrow[(h << 5) | jj];
          ow.x = fma(-cv, rk.x, ow.x);
          ow.y = fma(-cv, rk.y, ow.y);
          if (jj == kg && h == kh) { if (kc == 0) ow.x = cv; else ow.y = cv; }
          myrow[(h << 5) | jj] = ow;
        }
      }
      __syncthreads();
      if (i == k) {
#pragma unroll
        for (int jj = 0; jj < 32; ++jj) myrow[(h << 5) | jj] = rv[jj];
      }
      __syncthreads();
    }
  }

  // ---------------- Stage 2: K = B (R B^T) in 8 blocks of 12 cols --------
  // CONSTANT-INDEX register copy (blk&1 split) so Kc/Kc2 stay in VGPRs (round-5 spill fix).
  double Kc[24], Kc2[24];
  for (int blk = 0; blk < 8; ++blk) {
    // (a) Y[:, 12 cols] = R * g  (R[t][ia]: lane-consecutive -> conflict-free; R symmetric)
    {
      const float* gp[6];
#pragma unroll
      for (int jj = 0; jj < 6; ++jj) {
        int it = 12*blk + 6*hh + jj;
        gp[jj] = (it < DI) ? (Gb + it*NN) : (Ab + (it - DI)*NN);
      }
      double acc[6] = {0,0,0,0,0,0};
#pragma unroll 4
      for (int t = 0; t < NN; ++t) {
        double rv = ldsd[t*ROWD + ia];
#pragma unroll
        for (int jj = 0; jj < 6; ++jj)
          acc[jj] = fma(rv, (double)gp[jj][t], acc[jj]);
      }
      double2* yst = (double2*)(ldsd + YBUF + ia*12 + 6*hh);
#pragma unroll
      for (int p = 0; p < 3; ++p) yst[p] = make_double2(acc[2*p], acc[2*p+1]);
    }
    __syncthreads();
    // (b) K rows: Y reads wave-uniform (broadcast), B rows global
    {
      const int r2 = (ia < NZ) ? ia : 0;
      const float* brow = (r2 < DI) ? (Gb + r2*NN) : (Ab + (r2 - DI)*NN);
      double acc[6] = {0,0,0,0,0,0};
#pragma unroll 4
      for (int t = 0; t < NN; ++t) {
        double bvv = (double)brow[t];
        const double2* yr = (const double2*)(ldsd + YBUF + t*12 + 6*hh);
        double2 y0 = yr[0], y1 = yr[1], y2 = yr[2];
        acc[0] = fma(bvv, y0.x, acc[0]); acc[1] = fma(bvv, y0.y, acc[1]);
        acc[2] = fma(bvv, y1.x, acc[2]); acc[3] = fma(bvv, y1.y, acc[3]);
        acc[4] = fma(bvv, y2.x, acc[4]); acc[5] = fma(bvv, y2.y, acc[5]);
      }
      if (ia < NZ) {
#pragma unroll
        for (int jj = 0; jj < 6; ++jj) ldsd[KBUF + (6*hh + jj)*NZ + ia] = acc[jj];
      }
    }
    __syncthreads();
    if (w == (blk >> 1)) {
      if ((blk & 1) == 0) {
#pragma unroll
        for (int jj = 0; jj < 12; ++jj) {
          Kc [jj] = ldsd[KBUF + jj*NZ + l];
          Kc2[jj] = ldsd[KBUF + jj*NZ + 64 + (l & 31)];
        }
      } else {
#pragma unroll
        for (int jj = 0; jj < 12; ++jj) {
          Kc [12+jj] = ldsd[KBUF + jj*NZ + l];
          Kc2[12+jj] = ldsd[KBUF + jj*NZ + 64 + (l & 31)];
        }
      }
    }
    __syncthreads();
  }

  // ---------------- Stage 3a: c = q - G^T h - A^T b ----------------
  {
    double s = 0;
#pragma unroll 8
    for (int jc = 0; jc < 48; ++jc) {
      int j = 48*hh + jc;
      double coef = (j < DI) ? ldsd[HB + j] : ldsd[BB + j - DI];
      const float* src = (j < DI) ? (Gb + j*NN) : (Ab + (j - DI)*NN);
      s = fma(-(double)src[ia], coef, s);
    }
    ldsd[CPART + hh*128 + ia] = s;
  }
  __syncthreads();
  if (tid < NN) ldsd[CB + tid] = ldsd[QBUF + tid] + ldsd[CPART + tid] + ldsd[CPART + 128 + tid];
  __syncthreads();

  // ---------------- Stage 3b: v1 = R c, v2 = R q ----------------
  {
    double a = 0, b2 = 0;
#pragma unroll 4
    for (int tt = 0; tt < 64; ++tt) {
      int t = 64*hh + tt;
      double rv = ldsd[t*ROWD + ia];
      a  = fma(rv, ldsd[CB + t], a);
      b2 = fma(rv, ldsd[QBUF + t], b2);
    }
    ldsd[VP + hh*128 + ia] = a;
    ldsd[VP + 256 + hh*128 + ia] = b2;
  }
  __syncthreads();
  if (tid < NN) {
    ldsd[V1 + tid] = ldsd[VP + tid] + ldsd[VP + 128 + tid];
    ldsd[V2 + tid] = ldsd[VP + 256 + tid] + ldsd[VP + 384 + tid];
  }
  __syncthreads();

  // ---------------- Stage 3c: base = B v1, qB = B v2, scalars, z init ----------------
  {
    const int r2 = (ia < NZ) ? ia : 0;
    const float* brow = (r2 < DI) ? (Gb + r2*NN) : (Ab + (r2 - DI)*NN);
    const int voff = hh ? V2 : V1;
    double s = 0;
#pragma unroll 4
    for (int t = 0; t < NN; ++t) s = fma((double)brow[t], ldsd[voff + t], s);
    if (ia < NZ) ldsd[(hh ? QBV : BASEV) + ia] = s;
  }
  if (w == 0) {
    double pc = ldsd[V1+l]*ldsd[CB+l]   + ldsd[V1+64+l]*ldsd[CB+64+l];
    double pq = ldsd[V1+l]*ldsd[QBUF+l] + ldsd[V1+64+l]*ldsd[QBUF+64+l];
#pragma unroll
    for (int off = 32; off >= 1; off >>= 1) { pc += __shfl_xor(pc, off); pq += __shfl_xor(pq, off); }
    if (l == 0) { ldsd[CST] = pc; ldsd[CST+1] = pq; }
  }
  if (tid < NZ) ldsd[ZB + tid] = 0.0;
  __syncthreads();

  // per-wave loop registers
  double bAr = 0, bBr = 0, qAr = 0, h_r = 0, b_r = 0;
  if (w == 0)      { bAr = ldsd[BASEV + l]; bBr = ldsd[BASEV + 64 + (l&31)]; h_r = ldsd[HB + l]; }
  else if (w == 1) { b_r = ldsd[BB + (l & 31)]; }
  else if (w == 2) { bAr = ldsd[BASEV + l]; qAr = ldsd[QBV + l]; }
  else             { bBr = ldsd[BASEV + 64 + (l&31)]; qAr = ldsd[QBV + 64 + (l&31)]; }
  const double S_uc = ldsd[CST], S_qu = ldsd[CST + 1];
  double nu_r = 0, lam_r = 0;
  double res_prev = 1000.0, res_cur = -100.0;
  double zlo = 0.0, zhi = 0.0;

  // ---------------- ADMM loop on z (96-dim), 2 barriers/iter ----------------
  for (int it = 0; it < MAXIT; ++it) {
    zlo = ldsd[ZB + l];
    zhi = ldsd[ZB + 64 + (l & 31)];
    double a0, a1;
    if (w == 0) {
      a0 = bAr; a1 = bBr;     // base seeded once (wave 0)
#pragma unroll
      for (int j = 0; j < 24; ++j) {
        double zj = rld(zlo, j);
        a0 = fma(Kc[j], zj, a0); a1 = fma(Kc2[j], zj, a1);
      }
    } else if (w == 1) {
      a0 = 0; a1 = 0;
#pragma unroll
      for (int j = 0; j < 24; ++j) {
        double zj = rld(zlo, 24 + j);
        a0 = fma(Kc[j], zj, a0); a1 = fma(Kc2[j], zj, a1);
      }
    } else if (w == 2) {
      a0 = 0; a1 = 0;
#pragma unroll
      for (int j = 0; j < 16; ++j) {
        double zj = rld(zlo, 48 + j);
        a0 = fma(Kc[j], zj, a0); a1 = fma(Kc2[j], zj, a1);
      }
#pragma unroll
      for (int j = 0; j < 8; ++j) {
        double zj = rld(zhi, j);
        a0 = fma(Kc[16+j], zj, a0); a1 = fma(Kc2[16+j], zj, a1);
      }
    } else {
      a0 = 0; a1 = 0;
#pragma unroll
      for (int j = 0; j < 24; ++j) {
        double zj = rld(zhi, 8 + j);
        a0 = fma(Kc[j], zj, a0); a1 = fma(Kc2[j], zj, a1);
      }
    }
    ldsd[PLO + w*64 + l] = a0;                 // [wave][64]: conflict-free
    if (l < 32) ldsd[PHI + w*32 + l] = a1;     // [wave][32]: conflict-free
    __syncthreads();
    if (w == 0) {
      double y = (ldsd[PLO + l] + ldsd[PLO + 64 + l]) + (ldsd[PLO + 128 + l] + ldsd[PLO + 192 + l]);
      double sk = fmax(0.0, -nu_r - y + h_r);
      nu_r = nu_r + y + sk - h_r;
      ldsd[ZB + l] = nu_r + sk;
    } else if (w == 1) {
      const int lm = l & 31;
      double ym = (ldsd[PHI + lm] + ldsd[PHI + 32 + lm]) + (ldsd[PHI + 64 + lm] + ldsd[PHI + 96 + lm]);
      lam_r = lam_r + ym - b_r;
      if (l < 32) ldsd[ZB + 64 + l] = lam_r;
    } else if (w == 2) {
      double y = (ldsd[PLO + l] + ldsd[PLO + 64 + l]) + (ldsd[PLO + 128 + l] + ldsd[PLO + 192 + l]);
      double tv = fma(qAr, zlo, -0.5*(zlo*(bAr + y) + y*y));
#pragma unroll
      for (int off = 32; off >= 1; off >>= 1) tv += __shfl_xor(tv, off);
      if (l == 0) ldsd[OBJP] = tv;
    } else {
      const int lm = l & 31;
      double ym = (ldsd[PHI + lm] + ldsd[PHI + 32 + lm]) + (ldsd[PHI + 64 + lm] + ldsd[PHI + 96 + lm]);
      double tv = (l < 32) ? fma(qAr, zhi, -0.5*(zhi*(bBr + ym) + ym*ym)) : 0.0;
#pragma unroll
      for (int off = 32; off >= 1; off >>= 1) tv += __shfl_xor(tv, off);
      if (l == 0) ldsd[OBJP + 1] = tv;
    }
    __syncthreads();
    double obj = ldsd[OBJP] + ldsd[OBJP + 1] - 0.5*S_uc + S_qu;
    res_prev = res_cur; res_cur = obj;
    if (fabs((res_cur - res_prev) / res_prev) <= 1e-5) break;  // uniform (replicated f64)
  }

  // ---------------- Final: x = R (c + B^T z), z = top-of-stopping-iteration ----------------
  __syncthreads();
  {
    double s = 0;
#pragma unroll 8
    for (int jc = 0; jc < 48; ++jc) {
      int j = 48*hh + jc;
      double zj = (j < 64) ? rld(zlo, j) : rld(zhi, j - 64);
      const float* src = (j < DI) ? (Gb + j*NN) : (Ab + (j - DI)*NN);
      s = fma((double)src[ia], zj, s);
    }
    ldsd[FPART + hh*128 + ia] = s;
  }
  __syncthreads();
  if (tid < NN) ldsd[RHSV + tid] = ldsd[CB + tid] + ldsd[FPART + tid] + ldsd[FPART + 128 + tid];
  __syncthreads();
  {
    double s = 0;
#pragma unroll 4
    for (int tt = 0; tt < 64; ++tt) {
      int t = 64*hh + tt;
      s = fma(ldsd[t*ROWD + ia], ldsd[RHSV + t], s);   // R[t][ia] = R[ia][t], conflict-free
    }
    ldsd[XPART + hh*128 + ia] = s;
  }
  __syncthreads();
  if (tid < NN)
    out[(size_t)bidx * NN + tid] = (float)(ldsd[XPART + tid] + ldsd[XPART + 128 + tid]);
}

extern "C" void kernel_launch(void* const* d_in, const int* in_sizes, int n_in,
                              void* d_out, int out_size, void* d_ws, size_t ws_size,
                              hipStream_t stream) {
  (void)in_sizes; (void)n_in; (void)out_size; (void)d_ws; (void)ws_size;
  const float* Q = (const float*)d_in[0];
  const float* q = (const float*)d_in[1];
  const float* G = (const float*)d_in[2];
  const float* h = (const float*)d_in[3];
  const float* A = (const float*)d_in[4];
  const float* b = (const float*)d_in[5];
  float* out = (float*)d_out;
  const size_t lds_bytes = (size_t)LDS_DBL * sizeof(double);  // 159552
  altdiff_kernel<<<dim3(64), dim3(256), lds_bytes, stream>>>(Q, q, G, h, A, b, out);
}

// Round 7
// 745.796 us; speedup vs baseline: 3.1346x; 1.4816x over previous
//
#include <hip/hip_runtime.h>

#define NN 128
#define ME 32
#define DI 64
#define NZ 96
#define ROWD 130
#define MAXIT 5000

// ---- LDS layout (double offsets). R: [0, 16640). Total 19944 dbl = 159552 B.
#define OFF_UN 16640
#define ROWB  (OFF_UN)           // [2][128] sweep row-k buffer (phase 2)
#define COLB  (OFF_UN + 256)     // [2][128] sweep col-k buffer (phase 2)
#define PLO2  (OFF_UN)           // [2][4][64] lo partials (loop)
#define PHI2  (OFF_UN + 512)     // [2][4][32] hi partials (loop)
#define YBUF  (OFF_UN)           // [128][12] Y block (stage 2)
#define KBUF  (OFF_UN + 1536)    // [12][96] K cols (stage 2)
#define CPART (OFF_UN + 1024)    // [2][128] (stage 3a)
#define VP    (OFF_UN + 1280)    // [4][128] (stage 3b)
#define BASEV (OFF_UN + 1792)    // [96] (persists through loop)
#define QBV   (OFF_UN + 1888)    // [96] (persists through loop)
#define FPART (OFF_UN + 1024)    // [2][128] (final)
#define RHSV  (OFF_UN + 1280)    // [128] (final)
#define XPART (OFF_UN + 1408)    // [2][128] (final)
#define CB    (OFF_UN + 2688)    // [128] c
#define QBUF  (OFF_UN + 2816)    // [128] q
#define V1    (OFF_UN + 2944)    // [128] Rc
#define V2    (OFF_UN + 3072)    // [128] Rq
#define HB    (OFF_UN + 3200)    // [64]
#define BB    (OFF_UN + 3264)    // [32]
#define CST   (OFF_UN + 3296)    // [8]: 0=u.c 1=q.u
#define LDS_DBL (OFF_UN + 3304)  // 19944

// SGPR broadcast. CONTRACT: source computed by ALL 64 lanes (no divergence upstream).
__device__ __forceinline__ double rld(double v, int lane) {
  union { double d; unsigned long long u; } c; c.d = v;
  unsigned lo = (unsigned)c.u, hi = (unsigned)(c.u >> 32);
  lo = (unsigned)__builtin_amdgcn_readlane((int)lo, lane);
  hi = (unsigned)__builtin_amdgcn_readlane((int)hi, lane);
  c.u = (((unsigned long long)hi) << 32) | lo;
  return c.d;
}

__global__ __launch_bounds__(256, 1) void altdiff_kernel(
    const float* __restrict__ Qg, const float* __restrict__ qg,
    const float* __restrict__ Gg, const float* __restrict__ hg,
    const float* __restrict__ Ag, const float* __restrict__ bg,
    float* __restrict__ out)
{
  extern __shared__ double ldsd[];

  const int bidx = blockIdx.x;
  const int tid  = threadIdx.x;
  const int w    = tid >> 6;     // wave 0..3
  const int l    = tid & 63;     // lane
  const int lm   = l & 31;
  const int ia   = tid & 127;    // 128-split index
  const int hh   = tid >> 7;     // 0..1 (wave-uniform)

  const float* Qb = Qg + (size_t)bidx * NN * NN;
  const float* Ab = Ag + (size_t)bidx * ME * NN;
  const float* Gb = Gg + (size_t)bidx * DI * NN;
  const float* qb = qg + (size_t)bidx * NN;
  const float* hb = hg + (size_t)bidx * DI;
  const float* bv = bg + (size_t)bidx * ME;

  // stage h, b, q (f64)
  if (tid < DI) ldsd[HB + tid] = (double)hb[tid];
  else if (tid < DI + ME) ldsd[BB + tid - DI] = (double)bv[tid - DI];
  if (tid >= 128) ldsd[QBUF + tid - 128] = (double)qb[tid - 128];

  const int r = tid >> 4, c = tid & 15;   // 8x8 register tile at rows 8r.., cols 8c..
  double acc[8][8];                       // ALL indices compile-time constant (no scratch)

  // ---------------- Phase 1: M = Q + A^T A + G^T G (f64) -> registers ----------------
  {
    const float4* Q4 = (const float4*)Qb;
#pragma unroll
    for (int rr = 0; rr < 8; ++rr) {
      float4 q0 = Q4[((8*r+rr) << 5) + 2*c];
      float4 q1 = Q4[((8*r+rr) << 5) + 2*c + 1];
      acc[rr][0]=(double)q0.x; acc[rr][1]=(double)q0.y; acc[rr][2]=(double)q0.z; acc[rr][3]=(double)q0.w;
      acc[rr][4]=(double)q1.x; acc[rr][5]=(double)q1.y; acc[rr][6]=(double)q1.z; acc[rr][7]=(double)q1.w;
    }
    const float4* A4 = (const float4*)Ab;
    for (int m = 0; m < ME; ++m) {
      float4 u0 = A4[(m << 5) + 2*r], u1 = A4[(m << 5) + 2*r + 1];
      float4 v0 = A4[(m << 5) + 2*c], v1 = A4[(m << 5) + 2*c + 1];
      double uu[8] = {(double)u0.x,(double)u0.y,(double)u0.z,(double)u0.w,
                      (double)u1.x,(double)u1.y,(double)u1.z,(double)u1.w};
      double vv[8] = {(double)v0.x,(double)v0.y,(double)v0.z,(double)v0.w,
                      (double)v1.x,(double)v1.y,(double)v1.z,(double)v1.w};
#pragma unroll
      for (int rr = 0; rr < 8; ++rr)
#pragma unroll
        for (int cc = 0; cc < 8; ++cc)
          acc[rr][cc] = fma(uu[rr], vv[cc], acc[rr][cc]);
    }
    const float4* G4 = (const float4*)Gb;
    for (int d = 0; d < DI; ++d) {
      float4 u0 = G4[(d << 5) + 2*r], u1 = G4[(d << 5) + 2*r + 1];
      float4 v0 = G4[(d << 5) + 2*c], v1 = G4[(d << 5) + 2*c + 1];
      double uu[8] = {(double)u0.x,(double)u0.y,(double)u0.z,(double)u0.w,
                      (double)u1.x,(double)u1.y,(double)u1.z,(double)u1.w};
      double vv[8] = {(double)v0.x,(double)v0.y,(double)v0.z,(double)v0.w,
                      (double)v1.x,(double)v1.y,(double)v1.z,(double)v1.w};
#pragma unroll
      for (int rr = 0; rr < 8; ++rr)
#pragma unroll
        for (int cc = 0; cc < 8; ++cc)
          acc[rr][cc] = fma(uu[rr], vv[cc], acc[rr][cc]);
    }
  }

  // ---------------- Phase 2: register-tile sweep, 1 barrier/pivot, double-buffered ----------
  // Semantics identical to the validated LDS sweep: pivot row -> row/d (diag=-1/d);
  // pivot col -> cv = M[i][k]/d; generic -> M[i][j] - cv*M[k][j].
  {
    // publish pivot 0 (row 0 owners: r==0; col 0 owners: c==0)
    if (r == 0) {
#pragma unroll
      for (int cc = 0; cc < 8; ++cc) ldsd[ROWB + 8*c + cc] = acc[0][cc];
    }
    if (c == 0) {
#pragma unroll
      for (int rr = 0; rr < 8; ++rr) ldsd[COLB + 8*r + rr] = acc[rr][0];
    }
    __syncthreads();
    for (int k = 0; k < NN; ++k) {
      const int pb = (k & 1) << 7;
      const int krt = k >> 3, kcl = k & 7;
      double rowk[8], colv[8];
#pragma unroll
      for (int cc = 0; cc < 8; ++cc) rowk[cc] = ldsd[ROWB + pb + 8*c + cc];
#pragma unroll
      for (int rr = 0; rr < 8; ++rr) colv[rr] = ldsd[COLB + pb + 8*r + rr];
      const double dkk  = ldsd[ROWB + pb + k];     // same-address broadcast
      const double rcpd = 1.0 / dkk;               // pivots >= 1 (M >= I)
      double rdv[8];
#pragma unroll
      for (int cc = 0; cc < 8; ++cc) rdv[cc] = rowk[cc] * rcpd;
      const bool pivR = (r == krt), pivC = (c == krt);
#pragma unroll
      for (int rr = 0; rr < 8; ++rr) {
        const double cv = colv[rr] * rcpd;
        const bool pr = pivR && (rr == kcl);
#pragma unroll
        for (int cc = 0; cc < 8; ++cc) {
          double gen = fma(-cv, rowk[cc], acc[rr][cc]);
          acc[rr][cc] = pr ? rdv[cc] : gen;        // pivot row: divided row
        }
      }
      if (pivC) {                                  // pivot-col owners overwrite col k
#pragma unroll
        for (int cc = 0; cc < 8; ++cc) if (cc == kcl) {
#pragma unroll
          for (int rr = 0; rr < 8; ++rr) {
            const bool pr2 = pivR && (rr == kcl);
            acc[rr][cc] = pr2 ? -rcpd : colv[rr] * rcpd;
          }
        }
      }
      if (k < NN - 1) {                            // publish pivot k+1 into other buffer
        const int pb2 = ((k + 1) & 1) << 7;
        const int krt2 = (k + 1) >> 3, kcl2 = (k + 1) & 7;
        if (r == krt2) {
#pragma unroll
          for (int rr = 0; rr < 8; ++rr) if (rr == kcl2) {
#pragma unroll
            for (int cc = 0; cc < 8; ++cc) ldsd[ROWB + pb2 + 8*c + cc] = acc[rr][cc];
          }
        }
        if (c == krt2) {
#pragma unroll
          for (int cc = 0; cc < 8; ++cc) if (cc == kcl2) {
#pragma unroll
            for (int rr = 0; rr < 8; ++rr) ldsd[COLB + pb2 + 8*r + rr] = acc[rr][cc];
          }
        }
      }
      __syncthreads();
    }
    // write R to LDS (row-major, pitch ROWD) for stages 2/3b and the final solve
#pragma unroll
    for (int rr = 0; rr < 8; ++rr) {
      double2* dst = (double2*)(ldsd + (8*r+rr)*ROWD + 8*c);
#pragma unroll
      for (int t = 0; t < 4; ++t) dst[t] = make_double2(acc[rr][2*t], acc[rr][2*t+1]);
    }
  }
  __syncthreads();

  // ---------------- Stage 2: K = B (R B^T) in 8 blocks of 12 cols (validated r6) --------
  double Kc[24], Kc2[24];
  for (int blk = 0; blk < 8; ++blk) {
    {
      const float* gp[6];
#pragma unroll
      for (int jj = 0; jj < 6; ++jj) {
        int it = 12*blk + 6*hh + jj;
        gp[jj] = (it < DI) ? (Gb + it*NN) : (Ab + (it - DI)*NN);
      }
      double a2[6] = {0,0,0,0,0,0};
#pragma unroll 4
      for (int t = 0; t < NN; ++t) {
        double rv = ldsd[t*ROWD + ia];
#pragma unroll
        for (int jj = 0; jj < 6; ++jj)
          a2[jj] = fma(rv, (double)gp[jj][t], a2[jj]);
      }
      double2* yst = (double2*)(ldsd + YBUF + ia*12 + 6*hh);
#pragma unroll
      for (int p = 0; p < 3; ++p) yst[p] = make_double2(a2[2*p], a2[2*p+1]);
    }
    __syncthreads();
    {
      const int r2 = (ia < NZ) ? ia : 0;
      const float* brow = (r2 < DI) ? (Gb + r2*NN) : (Ab + (r2 - DI)*NN);
      double a2[6] = {0,0,0,0,0,0};
#pragma unroll 4
      for (int t = 0; t < NN; ++t) {
        double bvv = (double)brow[t];
        const double2* yr = (const double2*)(ldsd + YBUF + t*12 + 6*hh);
        double2 y0 = yr[0], y1 = yr[1], y2 = yr[2];
        a2[0] = fma(bvv, y0.x, a2[0]); a2[1] = fma(bvv, y0.y, a2[1]);
        a2[2] = fma(bvv, y1.x, a2[2]); a2[3] = fma(bvv, y1.y, a2[3]);
        a2[4] = fma(bvv, y2.x, a2[4]); a2[5] = fma(bvv, y2.y, a2[5]);
      }
      if (ia < NZ) {
#pragma unroll
        for (int jj = 0; jj < 6; ++jj) ldsd[KBUF + (6*hh + jj)*NZ + ia] = a2[jj];
      }
    }
    __syncthreads();
    if (w == (blk >> 1)) {          // CONSTANT-index copies (r5 spill fix)
      if ((blk & 1) == 0) {
#pragma unroll
        for (int jj = 0; jj < 12; ++jj) {
          Kc [jj] = ldsd[KBUF + jj*NZ + l];
          Kc2[jj] = ldsd[KBUF + jj*NZ + 64 + lm];
        }
      } else {
#pragma unroll
        for (int jj = 0; jj < 12; ++jj) {
          Kc [12+jj] = ldsd[KBUF + jj*NZ + l];
          Kc2[12+jj] = ldsd[KBUF + jj*NZ + 64 + lm];
        }
      }
    }
    __syncthreads();
  }

  // ---------------- Stage 3a: c = q - G^T h - A^T b ----------------
  {
    double s = 0;
#pragma unroll 8
    for (int jc = 0; jc < 48; ++jc) {
      int j = 48*hh + jc;
      double coef = (j < DI) ? ldsd[HB + j] : ldsd[BB + j - DI];
      const float* src = (j < DI) ? (Gb + j*NN) : (Ab + (j - DI)*NN);
      s = fma(-(double)src[ia], coef, s);
    }
    ldsd[CPART + hh*128 + ia] = s;
  }
  __syncthreads();
  if (tid < NN) ldsd[CB + tid] = ldsd[QBUF + tid] + ldsd[CPART + tid] + ldsd[CPART + 128 + tid];
  __syncthreads();

  // ---------------- Stage 3b: v1 = R c, v2 = R q ----------------
  {
    double a = 0, b2 = 0;
#pragma unroll 4
    for (int tt = 0; tt < 64; ++tt) {
      int t = 64*hh + tt;
      double rv = ldsd[t*ROWD + ia];
      a  = fma(rv, ldsd[CB + t], a);
      b2 = fma(rv, ldsd[QBUF + t], b2);
    }
    ldsd[VP + hh*128 + ia] = a;
    ldsd[VP + 256 + hh*128 + ia] = b2;
  }
  __syncthreads();
  if (tid < NN) {
    ldsd[V1 + tid] = ldsd[VP + tid] + ldsd[VP + 128 + tid];
    ldsd[V2 + tid] = ldsd[VP + 256 + tid] + ldsd[VP + 384 + tid];
  }
  __syncthreads();

  // ---------------- Stage 3c: base = B v1, qB = B v2, scalars ----------------
  {
    const int r2 = (ia < NZ) ? ia : 0;
    const float* brow = (r2 < DI) ? (Gb + r2*NN) : (Ab + (r2 - DI)*NN);
    const int voff = hh ? V2 : V1;
    double s = 0;
#pragma unroll 4
    for (int t = 0; t < NN; ++t) s = fma((double)brow[t], ldsd[voff + t], s);
    if (ia < NZ) ldsd[(hh ? QBV : BASEV) + ia] = s;
  }
  if (w == 0) {
    double pc = ldsd[V1+l]*ldsd[CB+l]   + ldsd[V1+64+l]*ldsd[CB+64+l];
    double pq = ldsd[V1+l]*ldsd[QBUF+l] + ldsd[V1+64+l]*ldsd[QBUF+64+l];
#pragma unroll
    for (int off = 32; off >= 1; off >>= 1) { pc += __shfl_xor(pc, off); pq += __shfl_xor(pq, off); }
    if (l == 0) { ldsd[CST] = pc; ldsd[CST+1] = pq; }
  }
  __syncthreads();

  // ---------------- Loop setup: state fully REPLICATED in every wave ----------------
  const double h_r   = ldsd[HB + l];
  const double b_r   = ldsd[BB + lm];
  const double baseA = ldsd[BASEV + l];
  const double baseB = ldsd[BASEV + 64 + lm];
  const double qvA   = ldsd[QBV + l];
  const double qvB   = ldsd[QBV + 64 + lm];
  const double S_uc  = ldsd[CST], S_qu = ldsd[CST + 1];
  double nu = 0.0, lam = 0.0;
  double zlo = 0.0, zhi = 0.0, zplo = 0.0, zphi = 0.0;
  double res_prev = 1000.0, res_cur = -100.0;

  // prologue: partials for iter 0 (z = 0 -> seed only), buffer 0
  {
    double a0 = (w == 0) ? baseA : 0.0;
    double a1 = (w == 0) ? baseB : 0.0;
    ldsd[PLO2 + w*64 + l] = a0;
    if (l < 32) ldsd[PHI2 + w*32 + l] = a1;
  }

  // ---------------- ADMM loop on z (96-dim): ONE barrier/iter, no z in LDS ----------------
  for (int it = 0; it < MAXIT; ++it) {
    __syncthreads();
    const int p = (it & 1) << 8;          // PLO2 buffer offset (256 dbl)
    const int ph = (it & 1) << 7;         // PHI2 buffer offset (128 dbl)
    double ylo = (ldsd[PLO2 + p + l]       + ldsd[PLO2 + p + 64 + l])
               + (ldsd[PLO2 + p + 128 + l] + ldsd[PLO2 + p + 192 + l]);
    double yhi = (ldsd[PHI2 + ph + lm]      + ldsd[PHI2 + ph + 32 + lm])
               + (ldsd[PHI2 + ph + 64 + lm] + ldsd[PHI2 + ph + 96 + lm]);
    zplo = zlo; zphi = zhi;               // z at top of this iteration (kept for x)
    double sk = fmax(0.0, -nu - ylo + h_r);
    nu  = nu + ylo + sk - h_r;
    zlo = nu + sk;
    lam = lam + yhi - b_r;
    zhi = lam;
    // matvec for NEXT iteration from the new z (registers; readlane broadcast)
    double a0, a1;
    if (w == 0) {
      a0 = baseA; a1 = baseB;
#pragma unroll
      for (int j = 0; j < 24; ++j) {
        double zj = rld(zlo, j);
        a0 = fma(Kc[j], zj, a0); a1 = fma(Kc2[j], zj, a1);
      }
    } else if (w == 1) {
      a0 = 0; a1 = 0;
#pragma unroll
      for (int j = 0; j < 24; ++j) {
        double zj = rld(zlo, 24 + j);
        a0 = fma(Kc[j], zj, a0); a1 = fma(Kc2[j], zj, a1);
      }
    } else if (w == 2) {
      a0 = 0; a1 = 0;
#pragma unroll
      for (int j = 0; j < 16; ++j) {
        double zj = rld(zlo, 48 + j);
        a0 = fma(Kc[j], zj, a0); a1 = fma(Kc2[j], zj, a1);
      }
#pragma unroll
      for (int j = 0; j < 8; ++j) {
        double zj = rld(zhi, j);
        a0 = fma(Kc[16+j], zj, a0); a1 = fma(Kc2[16+j], zj, a1);
      }
    } else {
      a0 = 0; a1 = 0;
#pragma unroll
      for (int j = 0; j < 24; ++j) {
        double zj = rld(zhi, 8 + j);
        a0 = fma(Kc[j], zj, a0); a1 = fma(Kc2[j], zj, a1);
      }
    }
    ldsd[PLO2 + (p ^ 256) + w*64 + l] = a0;
    if (l < 32) ldsd[PHI2 + (ph ^ 128) + w*32 + l] = a1;
    // objective(t) — replicated in every wave; butterfly (LDS pipe) overlaps matvec issue
    double tv = fma(qvA, zplo, -0.5*(zplo*(baseA + ylo) + ylo*ylo));
    tv += (l < 32) ? fma(qvB, zphi, -0.5*(zphi*(baseB + yhi) + yhi*yhi)) : 0.0;
#pragma unroll
    for (int off = 32; off >= 1; off >>= 1) tv += __shfl_xor(tv, off);
    double obj = tv - 0.5*S_uc + S_qu;
    res_prev = res_cur; res_cur = obj;
    if (fabs((res_cur - res_prev) / res_prev) <= 1e-5) break;  // identical in all threads
  }

  // ---------------- Final: x = R (c + B^T z), z = top-of-stopping-iteration ----------------
  __syncthreads();
  {
    double s = 0;
#pragma unroll 8
    for (int jc = 0; jc < 48; ++jc) {
      int j = 48*hh + jc;
      double zj = (j < 64) ? rld(zplo, j) : rld(zphi, j - 64);
      const float* src = (j < DI) ? (Gb + j*NN) : (Ab + (j - DI)*NN);
      s = fma((double)src[ia], zj, s);
    }
    ldsd[FPART + hh*128 + ia] = s;
  }
  __syncthreads();
  if (tid < NN) ldsd[RHSV + tid] = ldsd[CB + tid] + ldsd[FPART + tid] + ldsd[FPART + 128 + tid];
  __syncthreads();
  {
    double s = 0;
#pragma unroll 4
    for (int tt = 0; tt < 64; ++tt) {
      int t = 64*hh + tt;
      s = fma(ldsd[t*ROWD + ia], ldsd[RHSV + t], s);   // R[t][ia] = R[ia][t]
    }
    ldsd[XPART + hh*128 + ia] = s;
  }
  __syncthreads();
  if (tid < NN)
    out[(size_t)bidx * NN + tid] = (float)(ldsd[XPART + tid] + ldsd[XPART + 128 + tid]);
}

extern "C" void kernel_launch(void* const* d_in, const int* in_sizes, int n_in,
                              void* d_out, int out_size, void* d_ws, size_t ws_size,
                              hipStream_t stream) {
  (void)in_sizes; (void)n_in; (void)out_size; (void)d_ws; (void)ws_size;
  const float* Q = (const float*)d_in[0];
  const float* q = (const float*)d_in[1];
  const float* G = (const float*)d_in[2];
  const float* h = (const float*)d_in[3];
  const float* A = (const float*)d_in[4];
  const float* b = (const float*)d_in[5];
  float* out = (float*)d_out;
  const size_t lds_bytes = (size_t)LDS_DBL * sizeof(double);  // 159552
  altdiff_kernel<<<dim3(64), dim3(256), lds_bytes, stream>>>(Q, q, G, h, A, b, out);
}